// Round 8
// baseline (251.381 us; speedup 1.0000x reference)
//
#include <hip/hip_runtime.h>
#include <math.h>

// Problem constants (from reference): B=64, C=64, L=8192, fp32.
#define BB 64
#define CC 64
#define LL 8192
#define EPS_F 1.1920928955078125e-07f  // np.finfo(np.float32).eps

#define NB_STAT (BB * CC)               // 4096 stats blocks: one row each
#define NB_AUX  512                     // B*L/4/256 idx-convert blocks
#define ROW4 (LL / 4)                   // 2048 float4 per row

// Fused normalize: 4 f4/thread, 1024 f4/block -> 8192 blocks (128 per batch)
#define NB_NORM 8192

typedef float f4 __attribute__((ext_vector_type(4)));
typedef int   i4 __attribute__((ext_vector_type(4)));

// d_ws layout: partials[b][c] = float2{sum, sumsq}, 64*64 slots (32 KB).
// Every slot is written by tln_stats -> no zeroing pass, no atomics.

// Masked accumulate of one f4 whose first element has row-index l0.
#define ACC(v, l0, sacc, qacc) do {                       \
    float x0 = ((l0) + 0 < zp) ? (v).x : 0.0f;            \
    float x1 = ((l0) + 1 < zp) ? (v).y : 0.0f;            \
    float x2 = ((l0) + 2 < zp) ? (v).z : 0.0f;            \
    float x3 = ((l0) + 3 < zp) ? (v).w : 0.0f;            \
    sacc += (x0 + x1) + (x2 + x3);                        \
    qacc += (x0*x0 + x1*x1) + (x2*x2 + x3*x3);            \
} while (0)

// ---------------------------------------------------------------------------
// Kernel 1: blocks [0, NB_STAT) read ONE ENTIRE row data[b, c, :] (masked
// accumulate over the prefix). Reading the full row -- not just the prefix --
// is deliberate (r6 post-mortem): it warms ALL 128 MiB into L3 (256 MiB), so
// kernel 2's re-read is L3-served and degrades to a pure HBM write stream
// (r4 evidence: FETCH=102MB of 192MB read => L3 retention works). It also
// makes every block's work identical -> zero imbalance. Mask = 2 VALU/elem,
// ~8% of VALU at stream rate. 4 independent load streams x 2 windows.
// Blocks [NB_STAT, NB_STAT+NB_AUX) convert idxes (write pipe idle here).
// ---------------------------------------------------------------------------
__global__ __launch_bounds__(256) void tln_stats(const float* __restrict__ data,
                          const int* __restrict__ zero_pos,
                          const i4* __restrict__ idxes,
                          float2* __restrict__ partials,
                          f4* __restrict__ out_idx,
                          float* __restrict__ out_zp) {
    const int blk = blockIdx.x;
    const int tid = threadIdx.x;           // 0..255

    if (blk < NB_STAT) {
        const int b = blk >> 6;
        const int zp = zero_pos[b];
        const f4* p = (const f4*)(data + (size_t)blk * LL);  // blk == b*64+c

        float s0 = 0.f, s1 = 0.f, s2 = 0.f, s3 = 0.f;
        float q0 = 0.f, q1 = 0.f, q2 = 0.f, q3 = 0.f;
        #pragma unroll
        for (int w = 0; w < 2; ++w) {      // 2 windows x 4 streams = 8 f4/thr
            const int i = (w << 10) + tid;
            f4 a = p[i];
            f4 d = p[i + 256];
            f4 e = p[i + 512];
            f4 g = p[i + 768];
            const int l = i << 2;
            ACC(a, l,        s0, q0);
            ACC(d, l + 1024, s1, q1);
            ACC(e, l + 2048, s2, q2);
            ACC(g, l + 3072, s3, q3);
        }
        float sum = (s0 + s1) + (s2 + s3);
        float sq  = (q0 + q1) + (q2 + q3);

        // wave-64 reduce, then cross-wave via LDS
        #pragma unroll
        for (int off = 32; off > 0; off >>= 1) {
            sum += __shfl_down(sum, off);
            sq  += __shfl_down(sq, off);
        }
        __shared__ float lsum[4], lsq[4];
        const int wave = tid >> 6;
        const int lane = tid & 63;
        if (lane == 0) { lsum[wave] = sum; lsq[wave] = sq; }
        __syncthreads();
        if (tid == 0) {
            float2 pr;
            pr.x = lsum[0] + lsum[1] + lsum[2] + lsum[3];
            pr.y = lsq[0] + lsq[1] + lsq[2] + lsq[3];
            partials[blk] = pr;            // partials[b*64 + c]
        }
    } else {
        const int j = blk - NB_STAT;
        const int ii = j * 256 + tid;      // < 131072 = B*L/4
        i4 v = idxes[ii];
        f4 o = __builtin_convertvector(v, f4);
        __builtin_nontemporal_store(o, out_idx + ii);
        if (j == 0 && tid < BB) out_zp[tid] = (float)zero_pos[tid];
    }
}

// ---------------------------------------------------------------------------
// Kernel 2: pure normalize. 8192 blocks x 1024 f4 (4 per thread). Data loads
// issue FIRST (4 upfront -> 4 in flight, vs depth-2's ~1-2), butterfly stat
// recompute overlaps their latency, then 4 NT stores. Reads are L3-hot from
// kernel 1's full-slab warm; NT stores keep them from being evicted.
// ---------------------------------------------------------------------------
__global__ __launch_bounds__(256) void tln_fused(const f4* __restrict__ data4,
                          const float2* __restrict__ partials,
                          const int* __restrict__ zero_pos,
                          f4* __restrict__ out4) {
    const int blk = blockIdx.x;
    const int tid = threadIdx.x;
    const int b = blk >> 7;                // 128 blocks per batch
    const int lane = tid & 63;

    // issue the 4 data loads immediately (overlap the stats butterfly)
    const size_t base = (size_t)blk * 1024 + tid;
    f4 v0 = data4[base];
    f4 v1 = data4[base + 256];
    f4 v2 = data4[base + 512];
    f4 v3 = data4[base + 768];

    // one partial per lane, 6-step butterfly -> every lane has {S, Q}
    float2 p = partials[(b << 6) + lane];
    float s_ = p.x, q_ = p.y;
    #pragma unroll
    for (int off = 32; off > 0; off >>= 1) {
        s_ += __shfl_xor(s_, off);
        q_ += __shfl_xor(q_, off);
    }
    const float cnt  = (float)CC * (float)zero_pos[b];
    const float mean = s_ / cnt;
    const float var  = (q_ - cnt * mean * mean) / (cnt - 1.0f);
    const float inv  = 1.0f / (sqrtf(var) + EPS_F);

    __builtin_nontemporal_store((v0 - mean) * inv, out4 + base);
    __builtin_nontemporal_store((v1 - mean) * inv, out4 + base + 256);
    __builtin_nontemporal_store((v2 - mean) * inv, out4 + base + 512);
    __builtin_nontemporal_store((v3 - mean) * inv, out4 + base + 768);
}

extern "C" void kernel_launch(void* const* d_in, const int* in_sizes, int n_in,
                              void* d_out, int out_size, void* d_ws, size_t ws_size,
                              hipStream_t stream) {
    const float* data    = (const float*)d_in[0];
    const int* idxes     = (const int*)d_in[1];
    const int* zero_pos  = (const int*)d_in[2];

    float2* partials = (float2*)d_ws;       // B*C slots (32 KB), all overwritten

    float* out_data = (float*)d_out;                        // B*C*L
    float* out_idx  = out_data + (size_t)BB * CC * LL;      // B*L
    float* out_zp   = out_idx + (size_t)BB * LL;            // B

    tln_stats<<<NB_STAT + NB_AUX, 256, 0, stream>>>(
        data, zero_pos, (const i4*)idxes, partials, (f4*)out_idx, out_zp);

    tln_fused<<<NB_NORM, 256, 0, stream>>>(
        (const f4*)data, partials, zero_pos, (f4*)out_data);
}